// Round 7
// baseline (335.464 us; speedup 1.0000x reference)
//
#include <hip/hip_runtime.h>
#include <math.h>

#define DIN 256
#define HDIM 128
#define NCRIT 10

typedef __bf16 bf16;
typedef bf16 bf16x8 __attribute__((ext_vector_type(8)));
typedef float f32x4 __attribute__((ext_vector_type(4)));
typedef float f32x4v __attribute__((ext_vector_type(4)));
typedef unsigned u32x2v __attribute__((ext_vector_type(2)));
typedef unsigned u32x4v __attribute__((ext_vector_type(4)));

static inline size_t alignup(size_t x, size_t a) { return (x + a - 1) & ~(a - 1); }

__device__ inline float bflo(unsigned v) { return __uint_as_float(v << 16); }
__device__ inline float bfhi(unsigned v) { return __uint_as_float(v & 0xffff0000u); }

__device__ inline bf16x8 cvt8v(f32x4v v0, f32x4v v1) {
    bf16x8 w;
    w[0] = (bf16)v0[0]; w[1] = (bf16)v0[1]; w[2] = (bf16)v0[2]; w[3] = (bf16)v0[3];
    w[4] = (bf16)v1[0]; w[5] = (bf16)v1[1]; w[6] = (bf16)v1[2]; w[7] = (bf16)v1[3];
    return w;
}

__device__ inline void gl_lds16(const void* g, void* l) {
    __builtin_amdgcn_global_load_lds(
        (const __attribute__((address_space(1))) unsigned*)g,
        (__attribute__((address_space(3))) unsigned*)l, 16, 0, 0);
}

// ---------- CSR build (single atomic pass, x4 vectorized) ----------
__global__ void k_hist(const int* __restrict__ dst, int E, int* __restrict__ cnt,
                       int* __restrict__ epos) {
    int i4 = (blockIdx.x * 256 + threadIdx.x) * 4;
    if (i4 + 3 < E) {
        int4 d = *(const int4*)&dst[i4];
        int4 p;
        p.x = atomicAdd(&cnt[d.x], 1);
        p.y = atomicAdd(&cnt[d.y], 1);
        p.z = atomicAdd(&cnt[d.z], 1);
        p.w = atomicAdd(&cnt[d.w], 1);
        *(int4*)&epos[i4] = p;
    } else {
        for (int i = i4; i < E; ++i) epos[i] = atomicAdd(&cnt[dst[i]], 1);
    }
}

// ---------- alloc (wave scan + atomic base) fused with wconv ----------
__global__ void k_allocw(const int* __restrict__ cnt, int n, int* __restrict__ off,
                         int* __restrict__ total, int nAllocBlocks,
                         const float* __restrict__ Wl, const float* __restrict__ Wr,
                         const float* __restrict__ Wres, bf16* __restrict__ Wcat) {
    if ((int)blockIdx.x < nAllocBlocks) {
        int i = blockIdx.x * 256 + threadIdx.x;
        int lane = threadIdx.x & 63;
        int v = (i < n) ? cnt[i] : 0;
        int s = v;
        #pragma unroll
        for (int d = 1; d < 64; d <<= 1) {
            int t = __shfl_up(s, d, 64);
            if (lane >= d) s += t;
        }
        int excl = s - v;
        int wtot = __shfl(s, 63, 64);
        int base = 0;
        if (lane == 63) base = atomicAdd(total, wtot);
        base = __shfl(base, 63, 64);
        if (i < n) off[i] = base + excl;
    } else {
        int i = (blockIdx.x - nAllocBlocks) * 256 + threadIdx.x;
        int base = i * 4;
        if (base >= 384 * 256) return;
        int r = base >> 8;
        int c = base & 255;
        const float* W = (r < 128) ? Wl : ((r < 256) ? Wr : Wres);
        float4 v = *(const float4*)&W[(size_t)(r & 127) * 256 + c];
        bf16* o = &Wcat[base];
        o[0] = (bf16)v.x; o[1] = (bf16)v.y; o[2] = (bf16)v.z; o[3] = (bf16)v.w;
    }
}

__global__ void k_scatter(const int* __restrict__ src, const int* __restrict__ dst,
                          const int* __restrict__ epos, int E,
                          const int* __restrict__ off, int* __restrict__ sidx) {
    int i4 = (blockIdx.x * 256 + threadIdx.x) * 4;
    if (i4 + 3 < E) {
        int4 s = *(const int4*)&src[i4];
        int4 d = *(const int4*)&dst[i4];
        int4 p = *(const int4*)&epos[i4];
        sidx[off[d.x] + p.x] = s.x;
        sidx[off[d.y] + p.y] = s.y;
        sidx[off[d.z] + p.z] = s.z;
        sidx[off[d.w] + p.w] = s.w;
    } else {
        for (int i = i4; i < E; ++i) sidx[off[dst[i]] + epos[i]] = src[i];
    }
}

// ---------- MFMA GEMM: [y|z] = x @ Wcat^T, BM=64 BN=384 BK=32, dbuf + global_load_lds ----------
__global__ __launch_bounds__(256) void k_gemm(const float* __restrict__ x,
                                              const bf16* __restrict__ Wcat, int n,
                                              bf16* __restrict__ y, bf16* __restrict__ z) {
    __shared__ __align__(16) char smem[57344];
    int t = threadIdx.x;
    int wv = t >> 6, lane = t & 63;
    int node0 = blockIdx.x * 64;

    f32x4 acc[4][6] = {};

    int a_r = t >> 2, a_kq = t & 3;
    int a_gr = node0 + a_r;
    const float* a_src = &x[(size_t)a_gr * DIN + a_kq * 8];
    int a_woff = a_kq * 1024 + ((a_r ^ (a_kq << 1)) << 4);

    int gOff[6];
    const char* wcb = (const char*)Wcat;
    #pragma unroll
    for (int i = 0; i < 6; i++) {
        int LL = i * 256 + t;
        int kg = LL / 384;
        int c = LL - kg * 384;
        gOff[i] = c * 512 + kg * 16;
    }

    int f_kg = lane >> 4, f_l15 = lane & 15;
    int aRd[4];
    #pragma unroll
    for (int m = 0; m < 4; m++) {
        int r = m * 16 + f_l15;
        aRd[m] = f_kg * 1024 + ((r ^ (f_kg << 1)) << 4);
    }
    int bRd[6];
    #pragma unroll
    for (int nn = 0; nn < 6; nn++) {
        int c = wv * 96 + nn * 16 + f_l15;
        bRd[nn] = f_kg * 6144 + c * 16;
    }

    {
        f32x4v v0, v1;
        if (a_gr < n) {
            v0 = __builtin_nontemporal_load((const f32x4v*)a_src);
            v1 = __builtin_nontemporal_load((const f32x4v*)(a_src + 4));
        } else { v0 = (f32x4v)0.f; v1 = (f32x4v)0.f; }
        *(bf16x8*)(smem + 49152 + a_woff) = cvt8v(v0, v1);
        #pragma unroll
        for (int i = 0; i < 6; i++)
            gl_lds16(wcb + gOff[i], smem + i * 4096 + wv * 1024);
    }
    __syncthreads();

    #pragma unroll 2
    for (int s = 0; s < 8; ++s) {
        int cur = s & 1;
        f32x4v v0, v1;
        if (s < 7) {
            if (a_gr < n) {
                v0 = __builtin_nontemporal_load((const f32x4v*)(a_src + (s + 1) * 32));
                v1 = __builtin_nontemporal_load((const f32x4v*)(a_src + (s + 1) * 32 + 4));
            } else { v0 = (f32x4v)0.f; v1 = (f32x4v)0.f; }
            #pragma unroll
            for (int i = 0; i < 6; i++)
                gl_lds16(wcb + gOff[i] + (s + 1) * 64,
                         smem + (cur ^ 1) * 24576 + i * 4096 + wv * 1024);
        }
        bf16x8 afr[4], bfr[6];
        #pragma unroll
        for (int m = 0; m < 4; m++)
            afr[m] = *(const bf16x8*)(smem + 49152 + cur * 4096 + aRd[m]);
        #pragma unroll
        for (int nn = 0; nn < 6; nn++)
            bfr[nn] = *(const bf16x8*)(smem + cur * 24576 + bRd[nn]);
        __builtin_amdgcn_s_setprio(1);
        #pragma unroll
        for (int m = 0; m < 4; m++)
            #pragma unroll
            for (int nn = 0; nn < 6; nn++)
                acc[m][nn] = __builtin_amdgcn_mfma_f32_16x16x32_bf16(
                    afr[m], bfr[nn], acc[m][nn], 0, 0, 0);
        __builtin_amdgcn_s_setprio(0);
        if (s < 7)
            *(bf16x8*)(smem + 49152 + (cur ^ 1) * 4096 + a_woff) = cvt8v(v0, v1);
        __syncthreads();
    }

    bf16* Cs = (bf16*)smem;
    #pragma unroll
    for (int m = 0; m < 4; m++) {
        #pragma unroll
        for (int nn = 0; nn < 6; nn++) {
            int col = wv * 96 + nn * 16 + f_l15;
            int r0 = m * 16 + (f_kg << 2);
            #pragma unroll
            for (int j = 0; j < 4; j++)
                Cs[(r0 + j) * 392 + col] = (bf16)acc[m][nn][j];
        }
    }
    __syncthreads();

    {
        int r = t >> 2;
        int gr = node0 + r;
        if (gr < n) {
            #pragma unroll
            for (int u = 0; u < 4; u++) {
                int c = (t & 3) * 8 + u * 32;
                uint4 v = *(const uint4*)&Cs[r * 392 + c];
                *(uint4*)&y[(size_t)gr * HDIM + c] = v;
            }
            #pragma unroll
            for (int u = 0; u < 8; u++) {
                int c = (t & 3) * 8 + u * 32;
                u32x4v v = *(const u32x4v*)&Cs[r * 392 + 128 + c];
                __builtin_nontemporal_store(v, (u32x4v*)&z[(size_t)gr * 2 * HDIM + c]);
            }
        }
    }
}

// ---------- fused gather + epilogue: one wave per node, 8B/lane (2 rows/instr) ----------
__global__ __launch_bounds__(256) void k_gather(
    const bf16* __restrict__ y, const bf16* __restrict__ z,
    const int* __restrict__ off, const int* __restrict__ cnt, const int* __restrict__ sidx,
    const float* __restrict__ bl, const float* __restrict__ bres,
    const float* __restrict__ wscore, const float* __restrict__ bscore,
    const float* __restrict__ wcrit, const float* __restrict__ bcrit,
    const float* __restrict__ rrs, const float* __restrict__ palpha,
    int n, float* __restrict__ outF, float* __restrict__ outL)
{
    __shared__ bf16 wsb[11 * 128];
    int t = threadIdx.x;
    for (int i = t; i < 11 * 128; i += 256) {
        int q = i >> 7, c = i & 127;
        wsb[i] = (bf16)((q == 0) ? wscore[c] : wcrit[(size_t)(q - 1) * HDIM + c]);
    }
    __syncthreads();

    int node = blockIdx.x * 4 + (t >> 6);
    if (node >= n) return;
    int lane = t & 63, r2 = lane >> 5, c32 = lane & 31;

    // node-local streaming loads issued early, non-temporal (read-once)
    u32x2v zr = __builtin_nontemporal_load((const u32x2v*)&z[(size_t)node * 2 * HDIM + c32 * 4]);
    u32x2v zs = __builtin_nontemporal_load((const u32x2v*)&z[(size_t)node * 2 * HDIM + HDIM + c32 * 4]);
    float4 blv = *(const float4*)&bl[c32 * 4];
    float4 brv = *(const float4*)&bres[c32 * 4];

    const char* ybase = (const char*)y + c32 * 8;
    int beg = off[node], len = cnt[node];
    const int* sp = sidx + beg;

    float a0 = 0.f, a1 = 0.f, a2 = 0.f, a3 = 0.f;
    int e = 0;
    for (; e + 8 <= len; e += 8) {
        int i0 = __builtin_nontemporal_load(&sp[e + r2]);
        int i1 = __builtin_nontemporal_load(&sp[e + 2 + r2]);
        int i2 = __builtin_nontemporal_load(&sp[e + 4 + r2]);
        int i3 = __builtin_nontemporal_load(&sp[e + 6 + r2]);
        u32x2v v0 = *(const u32x2v*)(ybase + ((size_t)(unsigned)i0 << 8));
        u32x2v v1 = *(const u32x2v*)(ybase + ((size_t)(unsigned)i1 << 8));
        u32x2v v2 = *(const u32x2v*)(ybase + ((size_t)(unsigned)i2 << 8));
        u32x2v v3 = *(const u32x2v*)(ybase + ((size_t)(unsigned)i3 << 8));
        a0 += bflo(v0[0]) + bflo(v1[0]) + bflo(v2[0]) + bflo(v3[0]);
        a1 += bfhi(v0[0]) + bfhi(v1[0]) + bfhi(v2[0]) + bfhi(v3[0]);
        a2 += bflo(v0[1]) + bflo(v1[1]) + bflo(v2[1]) + bflo(v3[1]);
        a3 += bfhi(v0[1]) + bfhi(v1[1]) + bfhi(v2[1]) + bfhi(v3[1]);
    }
    for (; e < len; e += 2) {
        int slot = e + r2;
        int ii = sp[slot < len ? slot : len - 1];
        u32x2v v = *(const u32x2v*)(ybase + ((size_t)(unsigned)ii << 8));
        if (slot < len) {
            a0 += bflo(v[0]); a1 += bfhi(v[0]);
            a2 += bflo(v[1]); a3 += bfhi(v[1]);
        }
    }
    a0 += __shfl_xor(a0, 32, 64);
    a1 += __shfl_xor(a1, 32, 64);
    a2 += __shfl_xor(a2, 32, 64);
    a3 += __shfl_xor(a3, 32, 64);
    float inv = 1.f / fmaxf((float)len, 1.f);

    float h0 = fmaxf(a0 * inv + blv.x + bflo(zr[0]), 0.f) + bflo(zs[0]) + brv.x;
    float h1 = fmaxf(a1 * inv + blv.y + bfhi(zr[0]), 0.f) + bfhi(zs[0]) + brv.y;
    float h2 = fmaxf(a2 * inv + blv.z + bflo(zr[1]), 0.f) + bflo(zs[1]) + brv.z;
    float h3 = fmaxf(a3 * inv + blv.w + bfhi(zr[1]), 0.f) + bfhi(zs[1]) + brv.w;

    // split epilogue: half r2=0 handles q=0..5, half r2=1 handles q=6..10
    float p[6];
    #pragma unroll
    for (int qq = 0; qq < 6; qq++) {
        int q = r2 * 6 + qq;
        float s = 0.f;
        if (q < 11) {
            u32x2v w = *(const u32x2v*)&wsb[q * 128 + c32 * 4];
            s = h0 * bflo(w[0]) + h1 * bfhi(w[0]) + h2 * bflo(w[1]) + h3 * bfhi(w[1]);
        }
        #pragma unroll
        for (int d = 1; d < 32; d <<= 1)
            s += __shfl_xor(s, d, 64);
        p[qq] = s;
    }
    if ((lane & 31) == 0) {
        if (r2 == 0) {
            float al = palpha[0];
            float aa = 1.f / (1.f + expf(-al));
            float fs = aa * __builtin_nontemporal_load(&rrs[node]) + (1.f - aa) * (p[0] + bscore[0]);
            __builtin_nontemporal_store(fs, &outF[node]);
            #pragma unroll
            for (int qq = 1; qq < 6; qq++)
                __builtin_nontemporal_store(p[qq] + bcrit[qq - 1],
                                            &outL[(size_t)node * NCRIT + qq - 1]);
        } else {
            #pragma unroll
            for (int qq = 0; qq < 5; qq++)
                __builtin_nontemporal_store(p[qq] + bcrit[5 + qq],
                                            &outL[(size_t)node * NCRIT + 5 + qq]);
        }
    }
}

extern "C" void kernel_launch(void* const* d_in, const int* in_sizes, int n_in,
                              void* d_out, int out_size, void* d_ws, size_t ws_size,
                              hipStream_t stream) {
    const float* x      = (const float*)d_in[0];
    const int*   ei     = (const int*)d_in[1];
    const float* rrs    = (const float*)d_in[2];
    const float* Wl     = (const float*)d_in[3];
    const float* bl     = (const float*)d_in[4];
    const float* Wr     = (const float*)d_in[5];
    const float* Wres   = (const float*)d_in[6];
    const float* bres   = (const float*)d_in[7];
    const float* wscore = (const float*)d_in[8];
    const float* bscore = (const float*)d_in[9];
    const float* wcrit  = (const float*)d_in[10];
    const float* bcrit  = (const float*)d_in[11];
    const float* alpha  = (const float*)d_in[12];

    int N = in_sizes[0] / DIN;
    int E = in_sizes[1] / 2;
    const int* srcv = ei;
    const int* dstv = ei + E;

    char* p = (char*)d_ws;
    int* cnt   = (int*)p; p += alignup((size_t)N * 4, 256);
    int* total = (int*)p; p += 256;
    int* off   = (int*)p; p += alignup((size_t)N * 4, 256);
    int* epos  = (int*)p; p += alignup((size_t)E * 4, 256);
    int* sidx  = (int*)p; p += alignup((size_t)E * 4, 256);
    bf16* Wcat = (bf16*)p; p += alignup((size_t)384 * DIN * 2, 256);
    bf16* y    = (bf16*)p; p += alignup((size_t)N * HDIM * 2, 256);
    bf16* z    = (bf16*)p; p += alignup((size_t)N * 2 * HDIM * 2, 256);

    hipMemsetAsync(cnt, 0, (size_t)N * 4, stream);
    hipMemsetAsync(total, 0, 256, stream);

    k_hist<<<(E + 1023) / 1024, 256, 0, stream>>>(dstv, E, cnt, epos);
    int nAllocBlocks = (N + 255) / 256;
    k_allocw<<<nAllocBlocks + 96, 256, 0, stream>>>(cnt, N, off, total, nAllocBlocks,
                                                    Wl, Wr, Wres, Wcat);
    k_scatter<<<(E + 1023) / 1024, 256, 0, stream>>>(srcv, dstv, epos, E, off, sidx);

    k_gemm<<<(N + 63) / 64, 256, 0, stream>>>(x, Wcat, N, y, z);

    float* outF = (float*)d_out;
    float* outL = outF + N;
    k_gather<<<(N + 3) / 4, 256, 0, stream>>>(y, z, off, cnt, sidx, bl, bres,
                                              wscore, bscore, wcrit, bcrit,
                                              rrs, alpha, N, outF, outL);
}

// Round 8
// 309.066 us; speedup vs baseline: 1.0854x; 1.0854x over previous
//
#include <hip/hip_runtime.h>
#include <math.h>

#define DIN 256
#define HDIM 128
#define NCRIT 10

typedef __bf16 bf16;
typedef bf16 bf16x8 __attribute__((ext_vector_type(8)));
typedef float f32x4 __attribute__((ext_vector_type(4)));

static inline size_t alignup(size_t x, size_t a) { return (x + a - 1) & ~(a - 1); }

__device__ inline float bflo(unsigned v) { return __uint_as_float(v << 16); }
__device__ inline float bfhi(unsigned v) { return __uint_as_float(v & 0xffff0000u); }

__device__ inline bf16x8 cvt8(float4 v0, float4 v1) {
    bf16x8 w;
    w[0] = (bf16)v0.x; w[1] = (bf16)v0.y; w[2] = (bf16)v0.z; w[3] = (bf16)v0.w;
    w[4] = (bf16)v1.x; w[5] = (bf16)v1.y; w[6] = (bf16)v1.z; w[7] = (bf16)v1.w;
    return w;
}

__device__ inline void gl_lds16(const void* g, void* l) {
    __builtin_amdgcn_global_load_lds(
        (const __attribute__((address_space(1))) unsigned*)g,
        (__attribute__((address_space(3))) unsigned*)l, 16, 0, 0);
}

// ---------- CSR build (single atomic pass, scalar: max atomic concurrency) ----------
__global__ void k_hist(const int* __restrict__ dst, int E, int* __restrict__ cnt,
                       int* __restrict__ epos) {
    int i = blockIdx.x * 256 + threadIdx.x;
    if (i < E) epos[i] = atomicAdd(&cnt[dst[i]], 1);
}

// ---------- alloc (wave scan + atomic base) fused with wconv ----------
__global__ void k_allocw(const int* __restrict__ cnt, int n, int* __restrict__ off,
                         int* __restrict__ total, int nAllocBlocks,
                         const float* __restrict__ Wl, const float* __restrict__ Wr,
                         const float* __restrict__ Wres, bf16* __restrict__ Wcat) {
    if ((int)blockIdx.x < nAllocBlocks) {
        int i = blockIdx.x * 256 + threadIdx.x;
        int lane = threadIdx.x & 63;
        int v = (i < n) ? cnt[i] : 0;
        int s = v;
        #pragma unroll
        for (int d = 1; d < 64; d <<= 1) {
            int t = __shfl_up(s, d, 64);
            if (lane >= d) s += t;
        }
        int excl = s - v;
        int wtot = __shfl(s, 63, 64);
        int base = 0;
        if (lane == 63) base = atomicAdd(total, wtot);
        base = __shfl(base, 63, 64);
        if (i < n) off[i] = base + excl;
    } else {
        int i = (blockIdx.x - nAllocBlocks) * 256 + threadIdx.x;
        int base = i * 4;
        if (base >= 384 * 256) return;
        int r = base >> 8;
        int c = base & 255;
        const float* W = (r < 128) ? Wl : ((r < 256) ? Wr : Wres);
        float4 v = *(const float4*)&W[(size_t)(r & 127) * 256 + c];
        bf16* o = &Wcat[base];
        o[0] = (bf16)v.x; o[1] = (bf16)v.y; o[2] = (bf16)v.z; o[3] = (bf16)v.w;
    }
}

__global__ void k_scatter(const int* __restrict__ src, const int* __restrict__ dst,
                          const int* __restrict__ epos, int E,
                          const int* __restrict__ off, int* __restrict__ sidx) {
    int i = blockIdx.x * 256 + threadIdx.x;
    if (i < E) sidx[off[dst[i]] + epos[i]] = src[i];
}

// ---------- MFMA GEMM: [y|z] = x @ Wcat^T, BM=64 BN=384 BK=32, dbuf + global_load_lds ----------
__global__ __launch_bounds__(256) void k_gemm(const float* __restrict__ x,
                                              const bf16* __restrict__ Wcat, int n,
                                              bf16* __restrict__ y, bf16* __restrict__ z) {
    __shared__ __align__(16) char smem[57344];
    int t = threadIdx.x;
    int wv = t >> 6, lane = t & 63;
    int node0 = blockIdx.x * 64;

    f32x4 acc[4][6] = {};

    int a_r = t >> 2, a_kq = t & 3;
    int a_gr = node0 + a_r;
    const float* a_src = &x[(size_t)a_gr * DIN + a_kq * 8];
    int a_woff = a_kq * 1024 + ((a_r ^ (a_kq << 1)) << 4);

    int gOff[6];
    const char* wcb = (const char*)Wcat;
    #pragma unroll
    for (int i = 0; i < 6; i++) {
        int LL = i * 256 + t;
        int kg = LL / 384;
        int c = LL - kg * 384;
        gOff[i] = c * 512 + kg * 16;
    }

    int f_kg = lane >> 4, f_l15 = lane & 15;
    int aRd[4];
    #pragma unroll
    for (int m = 0; m < 4; m++) {
        int r = m * 16 + f_l15;
        aRd[m] = f_kg * 1024 + ((r ^ (f_kg << 1)) << 4);
    }
    int bRd[6];
    #pragma unroll
    for (int nn = 0; nn < 6; nn++) {
        int c = wv * 96 + nn * 16 + f_l15;
        bRd[nn] = f_kg * 6144 + c * 16;
    }

    {
        float4 v0, v1;
        if (a_gr < n) { v0 = *(const float4*)a_src; v1 = *(const float4*)(a_src + 4); }
        else { v0 = make_float4(0, 0, 0, 0); v1 = v0; }
        *(bf16x8*)(smem + 49152 + a_woff) = cvt8(v0, v1);
        #pragma unroll
        for (int i = 0; i < 6; i++)
            gl_lds16(wcb + gOff[i], smem + i * 4096 + wv * 1024);
    }
    __syncthreads();

    #pragma unroll 2
    for (int s = 0; s < 8; ++s) {
        int cur = s & 1;
        float4 v0, v1;
        if (s < 7) {
            if (a_gr < n) {
                v0 = *(const float4*)(a_src + (s + 1) * 32);
                v1 = *(const float4*)(a_src + (s + 1) * 32 + 4);
            } else { v0 = make_float4(0, 0, 0, 0); v1 = v0; }
            #pragma unroll
            for (int i = 0; i < 6; i++)
                gl_lds16(wcb + gOff[i] + (s + 1) * 64,
                         smem + (cur ^ 1) * 24576 + i * 4096 + wv * 1024);
        }
        bf16x8 afr[4], bfr[6];
        #pragma unroll
        for (int m = 0; m < 4; m++)
            afr[m] = *(const bf16x8*)(smem + 49152 + cur * 4096 + aRd[m]);
        #pragma unroll
        for (int nn = 0; nn < 6; nn++)
            bfr[nn] = *(const bf16x8*)(smem + cur * 24576 + bRd[nn]);
        __builtin_amdgcn_s_setprio(1);
        #pragma unroll
        for (int m = 0; m < 4; m++)
            #pragma unroll
            for (int nn = 0; nn < 6; nn++)
                acc[m][nn] = __builtin_amdgcn_mfma_f32_16x16x32_bf16(
                    afr[m], bfr[nn], acc[m][nn], 0, 0, 0);
        __builtin_amdgcn_s_setprio(0);
        if (s < 7)
            *(bf16x8*)(smem + 49152 + (cur ^ 1) * 4096 + a_woff) = cvt8(v0, v1);
        __syncthreads();
    }

    bf16* Cs = (bf16*)smem;
    #pragma unroll
    for (int m = 0; m < 4; m++) {
        #pragma unroll
        for (int nn = 0; nn < 6; nn++) {
            int col = wv * 96 + nn * 16 + f_l15;
            int r0 = m * 16 + (f_kg << 2);
            #pragma unroll
            for (int j = 0; j < 4; j++)
                Cs[(r0 + j) * 392 + col] = (bf16)acc[m][nn][j];
        }
    }
    __syncthreads();

    {
        int r = t >> 2;
        int gr = node0 + r;
        if (gr < n) {
            #pragma unroll
            for (int u = 0; u < 4; u++) {
                int c = (t & 3) * 8 + u * 32;
                uint4 v = *(const uint4*)&Cs[r * 392 + c];
                *(uint4*)&y[(size_t)gr * HDIM + c] = v;
            }
            #pragma unroll
            for (int u = 0; u < 8; u++) {
                int c = (t & 3) * 8 + u * 32;
                uint4 v = *(const uint4*)&Cs[r * 392 + 128 + c];
                *(uint4*)&z[(size_t)gr * 2 * HDIM + c] = v;
            }
        }
    }
}

// ---------- fused gather + epilogue: one wave per node, 8B/lane, 16-edge unroll ----------
__global__ __launch_bounds__(256) void k_gather(
    const bf16* __restrict__ y, const bf16* __restrict__ z,
    const int* __restrict__ off, const int* __restrict__ cnt, const int* __restrict__ sidx,
    const float* __restrict__ bl, const float* __restrict__ bres,
    const float* __restrict__ wscore, const float* __restrict__ bscore,
    const float* __restrict__ wcrit, const float* __restrict__ bcrit,
    const float* __restrict__ rrs, const float* __restrict__ palpha,
    int n, float* __restrict__ outF, float* __restrict__ outL)
{
    __shared__ bf16 wsb[11 * 128];
    int t = threadIdx.x;
    for (int i = t; i < 11 * 128; i += 256) {
        int q = i >> 7, c = i & 127;
        wsb[i] = (bf16)((q == 0) ? wscore[c] : wcrit[(size_t)(q - 1) * HDIM + c]);
    }
    __syncthreads();

    int node = blockIdx.x * 4 + (t >> 6);
    if (node >= n) return;
    int lane = t & 63, r2 = lane >> 5, c32 = lane & 31;

    // node-local loads issued early (hide under gather loop)
    uint2 zr = *(const uint2*)&z[(size_t)node * 2 * HDIM + c32 * 4];
    uint2 zs = *(const uint2*)&z[(size_t)node * 2 * HDIM + HDIM + c32 * 4];
    float4 blv = *(const float4*)&bl[c32 * 4];
    float4 brv = *(const float4*)&bres[c32 * 4];

    const char* ybase = (const char*)y + c32 * 8;
    int beg = off[node], len = cnt[node];
    const int* sp = sidx + beg;

    float a0 = 0.f, a1 = 0.f, a2 = 0.f, a3 = 0.f;
    int e = 0;
    // 16 edges per iteration: 8 independent row loads in flight
    for (; e + 16 <= len; e += 16) {
        int i0 = sp[e + r2];
        int i1 = sp[e + 2 + r2];
        int i2 = sp[e + 4 + r2];
        int i3 = sp[e + 6 + r2];
        int i4 = sp[e + 8 + r2];
        int i5 = sp[e + 10 + r2];
        int i6 = sp[e + 12 + r2];
        int i7 = sp[e + 14 + r2];
        uint2 v0 = *(const uint2*)(ybase + ((size_t)(unsigned)i0 << 8));
        uint2 v1 = *(const uint2*)(ybase + ((size_t)(unsigned)i1 << 8));
        uint2 v2 = *(const uint2*)(ybase + ((size_t)(unsigned)i2 << 8));
        uint2 v3 = *(const uint2*)(ybase + ((size_t)(unsigned)i3 << 8));
        uint2 v4 = *(const uint2*)(ybase + ((size_t)(unsigned)i4 << 8));
        uint2 v5 = *(const uint2*)(ybase + ((size_t)(unsigned)i5 << 8));
        uint2 v6 = *(const uint2*)(ybase + ((size_t)(unsigned)i6 << 8));
        uint2 v7 = *(const uint2*)(ybase + ((size_t)(unsigned)i7 << 8));
        a0 += bflo(v0.x) + bflo(v1.x) + bflo(v2.x) + bflo(v3.x)
            + bflo(v4.x) + bflo(v5.x) + bflo(v6.x) + bflo(v7.x);
        a1 += bfhi(v0.x) + bfhi(v1.x) + bfhi(v2.x) + bfhi(v3.x)
            + bfhi(v4.x) + bfhi(v5.x) + bfhi(v6.x) + bfhi(v7.x);
        a2 += bflo(v0.y) + bflo(v1.y) + bflo(v2.y) + bflo(v3.y)
            + bflo(v4.y) + bflo(v5.y) + bflo(v6.y) + bflo(v7.y);
        a3 += bfhi(v0.y) + bfhi(v1.y) + bfhi(v2.y) + bfhi(v3.y)
            + bfhi(v4.y) + bfhi(v5.y) + bfhi(v6.y) + bfhi(v7.y);
    }
    for (; e + 8 <= len; e += 8) {
        int i0 = sp[e + r2];
        int i1 = sp[e + 2 + r2];
        int i2 = sp[e + 4 + r2];
        int i3 = sp[e + 6 + r2];
        uint2 v0 = *(const uint2*)(ybase + ((size_t)(unsigned)i0 << 8));
        uint2 v1 = *(const uint2*)(ybase + ((size_t)(unsigned)i1 << 8));
        uint2 v2 = *(const uint2*)(ybase + ((size_t)(unsigned)i2 << 8));
        uint2 v3 = *(const uint2*)(ybase + ((size_t)(unsigned)i3 << 8));
        a0 += bflo(v0.x) + bflo(v1.x) + bflo(v2.x) + bflo(v3.x);
        a1 += bfhi(v0.x) + bfhi(v1.x) + bfhi(v2.x) + bfhi(v3.x);
        a2 += bflo(v0.y) + bflo(v1.y) + bflo(v2.y) + bflo(v3.y);
        a3 += bfhi(v0.y) + bfhi(v1.y) + bfhi(v2.y) + bfhi(v3.y);
    }
    for (; e < len; e += 2) {
        int slot = e + r2;
        int ii = sp[slot < len ? slot : len - 1];
        uint2 v = *(const uint2*)(ybase + ((size_t)(unsigned)ii << 8));
        if (slot < len) {
            a0 += bflo(v.x); a1 += bfhi(v.x);
            a2 += bflo(v.y); a3 += bfhi(v.y);
        }
    }
    a0 += __shfl_xor(a0, 32, 64);
    a1 += __shfl_xor(a1, 32, 64);
    a2 += __shfl_xor(a2, 32, 64);
    a3 += __shfl_xor(a3, 32, 64);
    float inv = 1.f / fmaxf((float)len, 1.f);

    float h0 = fmaxf(a0 * inv + blv.x + bflo(zr.x), 0.f) + bflo(zs.x) + brv.x;
    float h1 = fmaxf(a1 * inv + blv.y + bfhi(zr.x), 0.f) + bfhi(zs.x) + brv.y;
    float h2 = fmaxf(a2 * inv + blv.z + bflo(zr.y), 0.f) + bflo(zs.y) + brv.z;
    float h3 = fmaxf(a3 * inv + blv.w + bfhi(zr.y), 0.f) + bfhi(zs.y) + brv.w;

    // split epilogue: half r2=0 handles q=0..5, half r2=1 handles q=6..10
    float p[6];
    #pragma unroll
    for (int qq = 0; qq < 6; qq++) {
        int q = r2 * 6 + qq;
        float s = 0.f;
        if (q < 11) {
            uint2 w = *(const uint2*)&wsb[q * 128 + c32 * 4];
            s = h0 * bflo(w.x) + h1 * bfhi(w.x) + h2 * bflo(w.y) + h3 * bfhi(w.y);
        }
        #pragma unroll
        for (int d = 1; d < 32; d <<= 1)
            s += __shfl_xor(s, d, 64);
        p[qq] = s;
    }
    if ((lane & 31) == 0) {
        if (r2 == 0) {
            float al = palpha[0];
            float aa = 1.f / (1.f + expf(-al));
            outF[node] = aa * rrs[node] + (1.f - aa) * (p[0] + bscore[0]);
            #pragma unroll
            for (int qq = 1; qq < 6; qq++)
                outL[(size_t)node * NCRIT + qq - 1] = p[qq] + bcrit[qq - 1];
        } else {
            #pragma unroll
            for (int qq = 0; qq < 5; qq++)
                outL[(size_t)node * NCRIT + 5 + qq] = p[qq] + bcrit[5 + qq];
        }
    }
}

extern "C" void kernel_launch(void* const* d_in, const int* in_sizes, int n_in,
                              void* d_out, int out_size, void* d_ws, size_t ws_size,
                              hipStream_t stream) {
    const float* x      = (const float*)d_in[0];
    const int*   ei     = (const int*)d_in[1];
    const float* rrs    = (const float*)d_in[2];
    const float* Wl     = (const float*)d_in[3];
    const float* bl     = (const float*)d_in[4];
    const float* Wr     = (const float*)d_in[5];
    const float* Wres   = (const float*)d_in[6];
    const float* bres   = (const float*)d_in[7];
    const float* wscore = (const float*)d_in[8];
    const float* bscore = (const float*)d_in[9];
    const float* wcrit  = (const float*)d_in[10];
    const float* bcrit  = (const float*)d_in[11];
    const float* alpha  = (const float*)d_in[12];

    int N = in_sizes[0] / DIN;
    int E = in_sizes[1] / 2;
    const int* srcv = ei;
    const int* dstv = ei + E;

    char* p = (char*)d_ws;
    size_t cntPad = alignup((size_t)N * 4, 256);
    int* cnt   = (int*)p; p += cntPad;
    int* total = (int*)p; p += 256;
    int* off   = (int*)p; p += alignup((size_t)N * 4, 256);
    int* epos  = (int*)p; p += alignup((size_t)E * 4, 256);
    int* sidx  = (int*)p; p += alignup((size_t)E * 4, 256);
    bf16* Wcat = (bf16*)p; p += alignup((size_t)384 * DIN * 2, 256);
    bf16* y    = (bf16*)p; p += alignup((size_t)N * HDIM * 2, 256);
    bf16* z    = (bf16*)p; p += alignup((size_t)N * 2 * HDIM * 2, 256);

    // single memset covers cnt + total (adjacent)
    hipMemsetAsync(cnt, 0, cntPad + 256, stream);

    k_hist<<<(E + 255) / 256, 256, 0, stream>>>(dstv, E, cnt, epos);
    int nAllocBlocks = (N + 255) / 256;
    k_allocw<<<nAllocBlocks + 96, 256, 0, stream>>>(cnt, N, off, total, nAllocBlocks,
                                                    Wl, Wr, Wres, Wcat);
    k_scatter<<<(E + 255) / 256, 256, 0, stream>>>(srcv, dstv, epos, E, off, sidx);

    k_gemm<<<(N + 63) / 64, 256, 0, stream>>>(x, Wcat, N, y, z);

    float* outF = (float*)d_out;
    float* outL = outF + N;
    k_gather<<<(N + 3) / 4, 256, 0, stream>>>(y, z, off, cnt, sidx, bl, bres,
                                              wscore, bscore, wcrit, bcrit,
                                              rrs, alpha, N, outF, outL);
}